// Round 1
// baseline (297.517 us; speedup 1.0000x reference)
//
#include <hip/hip_runtime.h>
#include <math.h>

constexpr int BATCH = 256;

// ---------------------------------------------------------------------------
// Basis kernel: per (b, ii) compute 8 cubic B-spline basis values (K=3,
// extended grid 6 -> 12 knots) and silu(x). Write basis in BOTH layouts:
//   basisA[ii][b][8]  (for xout pass, threads = b)
//   basisB[b][ii][8]  (for stats pass, threads = ii)
// ---------------------------------------------------------------------------
template <int I>
__global__ __launch_bounds__(256) void basis_kernel(
    const float* __restrict__ X, const float* __restrict__ grid,
    float* __restrict__ basisA, float* __restrict__ basisB,
    float* __restrict__ siluT, float* __restrict__ siluN)
{
    int n  = blockIdx.x * 256 + threadIdx.x;   // n = b*I + ii
    int b  = n / I;
    int ii = n % I;
    float x = X[n];

    float g[6];
#pragma unroll
    for (int k = 0; k < 6; ++k) g[k] = grid[(size_t)ii * 6 + k];
    float h = (g[5] - g[0]) * 0.2f;

    float t[12];
    t[0] = g[0] - 3.f * h; t[1] = g[0] - 2.f * h; t[2] = g[0] - h;
#pragma unroll
    for (int k = 0; k < 6; ++k) t[3 + k] = g[k];
    t[9] = g[5] + h; t[10] = g[5] + 2.f * h; t[11] = g[5] + 3.f * h;

    float Bv[11];
#pragma unroll
    for (int j = 0; j < 11; ++j)
        Bv[j] = (x >= t[j] && x < t[j + 1]) ? 1.0f : 0.0f;

#pragma unroll
    for (int d = 1; d <= 3; ++d) {
#pragma unroll
        for (int j = 0; j + d < 11; ++j) {
            float left  = (x - t[j]) / (t[j + d] - t[j]);
            float right = (t[j + d + 1] - x) / (t[j + d + 1] - t[j + 1]);
            Bv[j] = left * Bv[j] + right * Bv[j + 1];
        }
    }

    float sv = x / (1.0f + expf(-x));

    float4 v0 = make_float4(Bv[0], Bv[1], Bv[2], Bv[3]);
    float4 v1 = make_float4(Bv[4], Bv[5], Bv[6], Bv[7]);

    float4* pB = (float4*)(basisB + (size_t)n * 8);
    pB[0] = v0; pB[1] = v1;
    float4* pA = (float4*)(basisA + ((size_t)ii * BATCH + b) * 8);
    pA[0] = v0; pA[1] = v1;
    siluN[n] = sv;
    siluT[(size_t)ii * BATCH + b] = sv;
}

// ---------------------------------------------------------------------------
// Pass A: x_out partials. threads = b (256). Each block: OTA outputs, one
// ii-range of I/NSPLIT. coef/sb/ssp indices are wave-uniform -> scalar loads.
// xpart layout: [NSPLIT][O][BATCH]
// ---------------------------------------------------------------------------
template <int I, int O, int OTA, int NSPLIT>
__global__ __launch_bounds__(256) void xout_kernel(
    const float* __restrict__ basisA, const float* __restrict__ siluT,
    const float* __restrict__ coef, const float* __restrict__ sb,
    const float* __restrict__ ssp, float* __restrict__ xpart)
{
    int b  = threadIdx.x;
    int og = blockIdx.x;            // O/OTA groups
    int sp = blockIdx.y;            // ii split index
    constexpr int IR = I / NSPLIT;
    int ii0 = sp * IR;

    float acc[OTA];
#pragma unroll
    for (int o = 0; o < OTA; ++o) acc[o] = 0.f;

    for (int ii = ii0; ii < ii0 + IR; ++ii) {
        const float4* ba = (const float4*)(basisA + ((size_t)ii * BATCH + b) * 8);
        float4 a0 = ba[0], a1 = ba[1];
        float sv = siluT[(size_t)ii * BATCH + b];
#pragma unroll
        for (int o = 0; o < OTA; ++o) {
            int s = (og * OTA + o) * I + ii;
            const float4* cf = (const float4*)(coef + (size_t)s * 8);
            float4 c0 = cf[0], c1 = cf[1];
            float spl = a0.x * c0.x + a0.y * c0.y + a0.z * c0.z + a0.w * c0.w
                      + a1.x * c1.x + a1.y * c1.y + a1.z * c1.z + a1.w * c1.w;
            acc[o] += sb[s] * sv + ssp[s] * spl;
        }
    }
#pragma unroll
    for (int o = 0; o < OTA; ++o) {
        int oo = og * OTA + o;
        xpart[((size_t)sp * O + oo) * BATCH + b] = acc[o];
    }
}

// Finalize x_out: sum NSPLIT partials + bias, write [b][O] row-major.
template <int O, int NSPLIT>
__global__ __launch_bounds__(256) void xout_fin(
    const float* __restrict__ xpart, const float* __restrict__ bias,
    float* __restrict__ dst)
{
    int idx = blockIdx.x * 256 + threadIdx.x;   // over O*BATCH, b fastest
    int oo = idx / BATCH, b = idx % BATCH;
    float v = bias[oo];
#pragma unroll
    for (int k = 0; k < NSPLIT; ++k)
        v += xpart[((size_t)k * O + oo) * BATCH + b];
    dst[(size_t)b * O + oo] = v;
}

// ---------------------------------------------------------------------------
// Pass B: stats. threads = ii (each owns I/256 ii's), register-accumulate
// sum|y|, sum y, sum y^2 over a b-chunk. coef in registers.
// spart layout: [NCHUNK][3][O*I]
// ---------------------------------------------------------------------------
template <int I, int O, int OTB, int NCHUNK>
__global__ __launch_bounds__(256) void stats_kernel(
    const float* __restrict__ basisB, const float* __restrict__ siluN,
    const float* __restrict__ coef, const float* __restrict__ sb,
    const float* __restrict__ ssp, float* __restrict__ spart)
{
    constexpr int IC  = I / 256;
    constexpr int BCH = BATCH / NCHUNK;
    int t  = threadIdx.x;
    int og = blockIdx.x;      // O/OTB
    int ch = blockIdx.y;      // b chunk

    float cf[OTB][IC][8];
    float sbr[OTB][IC], sspr[OTB][IC];
#pragma unroll
    for (int o = 0; o < OTB; ++o)
#pragma unroll
        for (int c = 0; c < IC; ++c) {
            int s = (og * OTB + o) * I + t + c * 256;
            const float4* p = (const float4*)(coef + (size_t)s * 8);
            float4 c0 = p[0], c1 = p[1];
            cf[o][c][0] = c0.x; cf[o][c][1] = c0.y; cf[o][c][2] = c0.z; cf[o][c][3] = c0.w;
            cf[o][c][4] = c1.x; cf[o][c][5] = c1.y; cf[o][c][6] = c1.z; cf[o][c][7] = c1.w;
            sbr[o][c] = sb[s]; sspr[o][c] = ssp[s];
        }

    float aab[OTB][IC], asum[OTB][IC], asq[OTB][IC];
#pragma unroll
    for (int o = 0; o < OTB; ++o)
#pragma unroll
        for (int c = 0; c < IC; ++c) { aab[o][c] = 0.f; asum[o][c] = 0.f; asq[o][c] = 0.f; }

    for (int bl = 0; bl < BCH; ++bl) {
        int b = ch * BCH + bl;
        float4 a0[IC], a1[IC]; float sv[IC];
#pragma unroll
        for (int c = 0; c < IC; ++c) {
            const float4* ba = (const float4*)(basisB + ((size_t)b * I + t + c * 256) * 8);
            a0[c] = ba[0]; a1[c] = ba[1];
            sv[c] = siluN[(size_t)b * I + t + c * 256];
        }
#pragma unroll
        for (int o = 0; o < OTB; ++o)
#pragma unroll
            for (int c = 0; c < IC; ++c) {
                float spl = a0[c].x * cf[o][c][0] + a0[c].y * cf[o][c][1]
                          + a0[c].z * cf[o][c][2] + a0[c].w * cf[o][c][3]
                          + a1[c].x * cf[o][c][4] + a1[c].y * cf[o][c][5]
                          + a1[c].z * cf[o][c][6] + a1[c].w * cf[o][c][7];
                float y = sbr[o][c] * sv[c] + sspr[o][c] * spl;
                aab[o][c] += fabsf(y);
                asum[o][c] += y;
                asq[o][c] = fmaf(y, y, asq[o][c]);
            }
    }

#pragma unroll
    for (int o = 0; o < OTB; ++o)
#pragma unroll
        for (int c = 0; c < IC; ++c) {
            int s = (og * OTB + o) * I + t + c * 256;
            size_t base = (size_t)ch * 3 * (size_t)O * I;
            spart[base + 0 * (size_t)O * I + s] = aab[o][c];
            spart[base + 1 * (size_t)O * I + s] = asum[o][c];
            spart[base + 2 * (size_t)O * I + s] = asq[o][c];
        }
}

// Finalize stats: combine chunks, apply /range and ddof=1 std.
__global__ __launch_bounds__(256) void stats_fin(
    const float* __restrict__ spart, const float* __restrict__ grid,
    float* __restrict__ sc, float* __restrict__ st, int size, int nchunk)
{
    int s = blockIdx.x * 256 + threadIdx.x;
    if (s >= size) return;
    float ab = 0.f, sm = 0.f, sq = 0.f;
    for (int k = 0; k < nchunk; ++k) {
        size_t base = (size_t)k * 3 * size;
        ab += spart[base + s];
        sm += spart[base + (size_t)size + s];
        sq += spart[base + 2 * (size_t)size + s];
    }
    float range = grid[(size_t)s * 6 + 5] - grid[(size_t)s * 6 + 0] + 1e-4f;
    sc[s] = (ab * (1.0f / BATCH)) / range;
    float var = (sq - sm * sm * (1.0f / BATCH)) * (1.0f / (BATCH - 1));
    st[s] = sqrtf(fmaxf(var, 0.0f));
}

// ---------------------------------------------------------------------------
extern "C" void kernel_launch(void* const* d_in, const int* in_sizes, int n_in,
                              void* d_out, int out_size, void* d_ws, size_t ws_size,
                              hipStream_t stream)
{
    const float* x     = (const float*)d_in[0];
    const float* grid0 = (const float*)d_in[1];
    const float* coef0 = (const float*)d_in[2];
    const float* sb0   = (const float*)d_in[3];
    const float* ssp0  = (const float*)d_in[4];
    const float* bias0 = (const float*)d_in[5];
    const float* grid1 = (const float*)d_in[6];
    const float* coef1 = (const float*)d_in[7];
    const float* sb1   = (const float*)d_in[8];
    const float* ssp1  = (const float*)d_in[9];
    const float* bias1 = (const float*)d_in[10];

    float* out = (float*)d_out;
    float* x2  = out;                 // (256,256)
    float* sc0 = out + 65536;         // (512,256)
    float* st0 = out + 196608;        // (512,256)
    float* sc1 = out + 327680;        // (256,512)
    float* st1 = out + 458752;        // (256,512)

    float* w = (float*)d_ws;
    float* basisA0 = w; w += 256 * 256 * 8;
    float* siluT0  = w; w += 256 * 256;
    float* basisB0 = w; w += 256 * 256 * 8;
    float* silu0   = w; w += 256 * 256;
    float* xmid    = w; w += 256 * 512;
    float* xpart0  = w; w += 8 * 512 * 256;
    float* spart0  = w; w += 4 * 3 * 512 * 256;
    float* basisA1 = w; w += 512 * 256 * 8;
    float* siluT1  = w; w += 512 * 256;
    float* basisB1 = w; w += 512 * 256 * 8;
    float* silu1   = w; w += 512 * 256;
    float* xpart1  = w; w += 16 * 256 * 256;
    float* spart1  = w; w += 4 * 3 * 256 * 512;

    // ---- layer 0: I=256, O=512 ----
    basis_kernel<256><<<(256 * 256) / 256, 256, 0, stream>>>(
        x, grid0, basisA0, basisB0, siluT0, silu0);
    xout_kernel<256, 512, 16, 8><<<dim3(512 / 16, 8), 256, 0, stream>>>(
        basisA0, siluT0, coef0, sb0, ssp0, xpart0);
    xout_fin<512, 8><<<(512 * 256) / 256, 256, 0, stream>>>(xpart0, bias0, xmid);
    stats_kernel<256, 512, 8, 4><<<dim3(512 / 8, 4), 256, 0, stream>>>(
        basisB0, silu0, coef0, sb0, ssp0, spart0);
    stats_fin<<<(512 * 256) / 256, 256, 0, stream>>>(
        spart0, grid0, sc0, st0, 512 * 256, 4);

    // ---- layer 1: I=512, O=256 ----
    basis_kernel<512><<<(256 * 512) / 256, 256, 0, stream>>>(
        xmid, grid1, basisA1, basisB1, siluT1, silu1);
    xout_kernel<512, 256, 16, 16><<<dim3(256 / 16, 16), 256, 0, stream>>>(
        basisA1, siluT1, coef1, sb1, ssp1, xpart1);
    xout_fin<256, 16><<<(256 * 256) / 256, 256, 0, stream>>>(xpart1, bias1, x2);
    stats_kernel<512, 256, 4, 4><<<dim3(256 / 4, 4), 256, 0, stream>>>(
        basisB1, silu1, coef1, sb1, ssp1, spart1);
    stats_fin<<<(256 * 512) / 256, 256, 0, stream>>>(
        spart1, grid1, sc1, st1, 256 * 512, 4);
}

// Round 2
// 146.392 us; speedup vs baseline: 2.0323x; 2.0323x over previous
//
#include <hip/hip_runtime.h>
#include <math.h>

constexpr int BATCH = 256;

// ---------------------------------------------------------------------------
// Merge kernel: wc[s*12 + k] = ssp[s]*coef[s*8+k] for k<8; wc[s*12+8] = sb[s].
// 12-float records keep every float4 16B-aligned.
// ---------------------------------------------------------------------------
__global__ __launch_bounds__(256) void merge_kernel(
    const float* __restrict__ coef, const float* __restrict__ ssp,
    const float* __restrict__ sb, float* __restrict__ wc, int size)
{
    int s = blockIdx.x * 256 + threadIdx.x;
    if (s >= size) return;
    float sspv = ssp[s], sbv = sb[s];
    const float4* c = (const float4*)(coef + (size_t)s * 8);
    float4 c0 = c[0], c1 = c[1];
    float4* w = (float4*)(wc + (size_t)s * 12);
    w[0] = make_float4(sspv * c0.x, sspv * c0.y, sspv * c0.z, sspv * c0.w);
    w[1] = make_float4(sspv * c1.x, sspv * c1.y, sspv * c1.z, sspv * c1.w);
    w[2] = make_float4(sbv, 0.f, 0.f, 0.f);
}

// ---------------------------------------------------------------------------
// Basis kernel: per (b, ii) compute 8 cubic B-spline basis values + silu(x).
//   basA4[(ii*2+h)*B + b]  (float4, h=0/1)  -> coalesced loads in xout (threads=b)
//   siluT[ii*B + b]
//   basisB[(b*I+ii)*8], siluN[b*I+ii]       -> for stats pass (threads = ii)
// ---------------------------------------------------------------------------
template <int I>
__global__ __launch_bounds__(256) void basis_kernel(
    const float* __restrict__ X, const float* __restrict__ grid,
    float4* __restrict__ basA4, float* __restrict__ siluT,
    float* __restrict__ basisB, float* __restrict__ siluN)
{
    int n  = blockIdx.x * 256 + threadIdx.x;   // n = b*I + ii
    int b  = n / I;
    int ii = n % I;
    float x = X[n];

    float g[6];
#pragma unroll
    for (int k = 0; k < 6; ++k) g[k] = grid[(size_t)ii * 6 + k];
    float h = (g[5] - g[0]) * 0.2f;

    float t[12];
    t[0] = g[0] - 3.f * h; t[1] = g[0] - 2.f * h; t[2] = g[0] - h;
#pragma unroll
    for (int k = 0; k < 6; ++k) t[3 + k] = g[k];
    t[9] = g[5] + h; t[10] = g[5] + 2.f * h; t[11] = g[5] + 3.f * h;

    float Bv[11];
#pragma unroll
    for (int j = 0; j < 11; ++j)
        Bv[j] = (x >= t[j] && x < t[j + 1]) ? 1.0f : 0.0f;

#pragma unroll
    for (int d = 1; d <= 3; ++d) {
#pragma unroll
        for (int j = 0; j + d < 11; ++j) {
            float left  = (x - t[j]) / (t[j + d] - t[j]);
            float right = (t[j + d + 1] - x) / (t[j + d + 1] - t[j + 1]);
            Bv[j] = left * Bv[j] + right * Bv[j + 1];
        }
    }

    float sv = x / (1.0f + expf(-x));

    float4 v0 = make_float4(Bv[0], Bv[1], Bv[2], Bv[3]);
    float4 v1 = make_float4(Bv[4], Bv[5], Bv[6], Bv[7]);

    basA4[(size_t)(ii * 2 + 0) * BATCH + b] = v0;
    basA4[(size_t)(ii * 2 + 1) * BATCH + b] = v1;
    siluT[(size_t)ii * BATCH + b] = sv;

    float4* pB = (float4*)(basisB + (size_t)n * 8);
    pB[0] = v0; pB[1] = v1;
    siluN[n] = sv;
}

// ---------------------------------------------------------------------------
// xout v3: register-tiled sweep. Block = 256 threads = 4 waves.
// Block covers OTA=8 outputs x IR=16 inputs; wave w owns o_local = w*2+q.
// Thread holds 4 b's (lane + 64j) x 2 o's accumulators.
// wc tile staged in LDS (broadcast reads); basis read coalesced from global.
// xpart layout: [NSPLIT][O][BATCH]
// ---------------------------------------------------------------------------
template <int I, int O, int OTA, int IR>
__global__ __launch_bounds__(256) void xout3_kernel(
    const float4* __restrict__ basA4, const float* __restrict__ siluT,
    const float* __restrict__ wc, float* __restrict__ xpart)
{
    constexpr int OW  = OTA / 4;          // o's per wave
    constexpr int NF4 = OTA * IR * 3;     // float4's in LDS tile
    __shared__ float4 wcs[NF4];

    int t = threadIdx.x, lane = t & 63, w = t >> 6;
    int og = blockIdx.x, sp = blockIdx.y;
    int ii0 = sp * IR;

    for (int f = t; f < NF4; f += 256) {
        int o_r = f / (IR * 3), c = f % (IR * 3);
        wcs[f] = ((const float4*)(wc + ((size_t)(og * OTA + o_r) * I + ii0) * 12))[c];
    }
    __syncthreads();

    float acc[4][OW];
#pragma unroll
    for (int j = 0; j < 4; ++j)
#pragma unroll
        for (int q = 0; q < OW; ++q) acc[j][q] = 0.f;

    for (int i = 0; i < IR; ++i) {
        int ii = ii0 + i;
        float4 a0[4], a1[4]; float sv[4];
#pragma unroll
        for (int j = 0; j < 4; ++j) {
            int b = lane + 64 * j;
            a0[j] = basA4[(size_t)(ii * 2 + 0) * BATCH + b];
            a1[j] = basA4[(size_t)(ii * 2 + 1) * BATCH + b];
            sv[j] = siluT[(size_t)ii * BATCH + b];
        }
#pragma unroll
        for (int q = 0; q < OW; ++q) {
            const float* wr = (const float*)&wcs[((w * OW + q) * IR + i) * 3];
            float4 c0 = ((const float4*)wr)[0];
            float4 c1 = ((const float4*)wr)[1];
            float c8 = wr[8];
#pragma unroll
            for (int j = 0; j < 4; ++j) {
                acc[j][q] += a0[j].x * c0.x + a0[j].y * c0.y + a0[j].z * c0.z + a0[j].w * c0.w
                           + a1[j].x * c1.x + a1[j].y * c1.y + a1[j].z * c1.z + a1[j].w * c1.w
                           + sv[j] * c8;
            }
        }
    }

#pragma unroll
    for (int q = 0; q < OW; ++q) {
        int oo = og * OTA + w * OW + q;
#pragma unroll
        for (int j = 0; j < 4; ++j)
            xpart[((size_t)sp * O + oo) * BATCH + lane + 64 * j] = acc[j][q];
    }
}

// Finalize x_out: sum NSPLIT partials + bias, write [b][O] row-major.
template <int O, int NSPLIT>
__global__ __launch_bounds__(256) void xout_fin(
    const float* __restrict__ xpart, const float* __restrict__ bias,
    float* __restrict__ dst)
{
    int idx = blockIdx.x * 256 + threadIdx.x;   // over O*BATCH, b fastest
    int oo = idx / BATCH, b = idx % BATCH;
    float v = bias[oo];
#pragma unroll
    for (int k = 0; k < NSPLIT; ++k)
        v += xpart[((size_t)k * O + oo) * BATCH + b];
    dst[(size_t)b * O + oo] = v;
}

// ---------------------------------------------------------------------------
// Stats: threads = ii, register-accumulate sum|y|, sum y, sum y^2 over b-chunk.
// spart layout: [NCHUNK][3][O*I]
// ---------------------------------------------------------------------------
template <int I, int O, int OTB, int NCHUNK>
__global__ __launch_bounds__(256) void stats_kernel(
    const float* __restrict__ basisB, const float* __restrict__ siluN,
    const float* __restrict__ coef, const float* __restrict__ sb,
    const float* __restrict__ ssp, float* __restrict__ spart)
{
    constexpr int IC  = I / 256;
    constexpr int BCH = BATCH / NCHUNK;
    int t  = threadIdx.x;
    int og = blockIdx.x;      // O/OTB
    int ch = blockIdx.y;      // b chunk

    float cf[OTB][IC][8];
    float sbr[OTB][IC], sspr[OTB][IC];
#pragma unroll
    for (int o = 0; o < OTB; ++o)
#pragma unroll
        for (int c = 0; c < IC; ++c) {
            int s = (og * OTB + o) * I + t + c * 256;
            const float4* p = (const float4*)(coef + (size_t)s * 8);
            float4 c0 = p[0], c1 = p[1];
            cf[o][c][0] = c0.x; cf[o][c][1] = c0.y; cf[o][c][2] = c0.z; cf[o][c][3] = c0.w;
            cf[o][c][4] = c1.x; cf[o][c][5] = c1.y; cf[o][c][6] = c1.z; cf[o][c][7] = c1.w;
            sbr[o][c] = sb[s]; sspr[o][c] = ssp[s];
        }

    float aab[OTB][IC], asum[OTB][IC], asq[OTB][IC];
#pragma unroll
    for (int o = 0; o < OTB; ++o)
#pragma unroll
        for (int c = 0; c < IC; ++c) { aab[o][c] = 0.f; asum[o][c] = 0.f; asq[o][c] = 0.f; }

    for (int bl = 0; bl < BCH; ++bl) {
        int b = ch * BCH + bl;
        float4 a0[IC], a1[IC]; float sv[IC];
#pragma unroll
        for (int c = 0; c < IC; ++c) {
            const float4* ba = (const float4*)(basisB + ((size_t)b * I + t + c * 256) * 8);
            a0[c] = ba[0]; a1[c] = ba[1];
            sv[c] = siluN[(size_t)b * I + t + c * 256];
        }
#pragma unroll
        for (int o = 0; o < OTB; ++o)
#pragma unroll
            for (int c = 0; c < IC; ++c) {
                float spl = a0[c].x * cf[o][c][0] + a0[c].y * cf[o][c][1]
                          + a0[c].z * cf[o][c][2] + a0[c].w * cf[o][c][3]
                          + a1[c].x * cf[o][c][4] + a1[c].y * cf[o][c][5]
                          + a1[c].z * cf[o][c][6] + a1[c].w * cf[o][c][7];
                float y = sbr[o][c] * sv[c] + sspr[o][c] * spl;
                aab[o][c] += fabsf(y);
                asum[o][c] += y;
                asq[o][c] = fmaf(y, y, asq[o][c]);
            }
    }

#pragma unroll
    for (int o = 0; o < OTB; ++o)
#pragma unroll
        for (int c = 0; c < IC; ++c) {
            int s = (og * OTB + o) * I + t + c * 256;
            size_t base = (size_t)ch * 3 * (size_t)O * I;
            spart[base + 0 * (size_t)O * I + s] = aab[o][c];
            spart[base + 1 * (size_t)O * I + s] = asum[o][c];
            spart[base + 2 * (size_t)O * I + s] = asq[o][c];
        }
}

// Finalize stats: combine chunks, apply /range and ddof=1 std.
__global__ __launch_bounds__(256) void stats_fin(
    const float* __restrict__ spart, const float* __restrict__ grid,
    float* __restrict__ sc, float* __restrict__ st, int size, int nchunk)
{
    int s = blockIdx.x * 256 + threadIdx.x;
    if (s >= size) return;
    float ab = 0.f, sm = 0.f, sq = 0.f;
    for (int k = 0; k < nchunk; ++k) {
        size_t base = (size_t)k * 3 * size;
        ab += spart[base + s];
        sm += spart[base + (size_t)size + s];
        sq += spart[base + 2 * (size_t)size + s];
    }
    float range = grid[(size_t)s * 6 + 5] - grid[(size_t)s * 6 + 0] + 1e-4f;
    sc[s] = (ab * (1.0f / BATCH)) / range;
    float var = (sq - sm * sm * (1.0f / BATCH)) * (1.0f / (BATCH - 1));
    st[s] = sqrtf(fmaxf(var, 0.0f));
}

// ---------------------------------------------------------------------------
extern "C" void kernel_launch(void* const* d_in, const int* in_sizes, int n_in,
                              void* d_out, int out_size, void* d_ws, size_t ws_size,
                              hipStream_t stream)
{
    const float* x     = (const float*)d_in[0];
    const float* grid0 = (const float*)d_in[1];
    const float* coef0 = (const float*)d_in[2];
    const float* sb0   = (const float*)d_in[3];
    const float* ssp0  = (const float*)d_in[4];
    const float* bias0 = (const float*)d_in[5];
    const float* grid1 = (const float*)d_in[6];
    const float* coef1 = (const float*)d_in[7];
    const float* sb1   = (const float*)d_in[8];
    const float* ssp1  = (const float*)d_in[9];
    const float* bias1 = (const float*)d_in[10];

    float* out = (float*)d_out;
    float* x2  = out;                 // (256,256)
    float* sc0 = out + 65536;         // (512,256)
    float* st0 = out + 196608;        // (512,256)
    float* sc1 = out + 327680;        // (256,512)
    float* st1 = out + 458752;        // (256,512)

    // Workspace layout (aliased regions are sequenced by stream order):
    float* w = (float*)d_ws;
    float* basA0  = w; w += 256 * 256 * 8;    // float4-packed basis, layer0
    float* siluT0 = w; w += 256 * 256;
    float* basB0  = w; w += 256 * 256 * 8;
    float* silu0  = w; w += 256 * 256;
    float* xmid   = w; w += 256 * 512;
    float* wcS    = w; w += 512 * 256 * 12;   // shared: wc0 then wc1
    float* partS  = w; w += 32 * 256 * 256;   // shared: xpart0/spart0/xpart1/spart1 (2.1M floats)
    float* basA1  = w; w += 512 * 256 * 8;
    float* siluT1 = w; w += 512 * 256;
    float* basB1  = w; w += 512 * 256 * 8;
    float* silu1  = w; w += 512 * 256;

    // ---- layer 0: I=256, O=512 ----
    merge_kernel<<<512, 256, 0, stream>>>(coef0, ssp0, sb0, wcS, 512 * 256);
    basis_kernel<256><<<(256 * 256) / 256, 256, 0, stream>>>(
        x, grid0, (float4*)basA0, siluT0, basB0, silu0);
    // OTA=8, IR=16 -> grid (512/8=64, 256/16=16) = 1024 blocks
    xout3_kernel<256, 512, 8, 16><<<dim3(64, 16), 256, 0, stream>>>(
        (const float4*)basA0, siluT0, wcS, partS);
    xout_fin<512, 16><<<(512 * 256) / 256, 256, 0, stream>>>(partS, bias0, xmid);
    stats_kernel<256, 512, 8, 4><<<dim3(512 / 8, 4), 256, 0, stream>>>(
        basB0, silu0, coef0, sb0, ssp0, partS);
    stats_fin<<<(512 * 256) / 256, 256, 0, stream>>>(
        partS, grid0, sc0, st0, 512 * 256, 4);

    // ---- layer 1: I=512, O=256 ----
    merge_kernel<<<512, 256, 0, stream>>>(coef1, ssp1, sb1, wcS, 256 * 512);
    basis_kernel<512><<<(256 * 512) / 256, 256, 0, stream>>>(
        xmid, grid1, (float4*)basA1, siluT1, basB1, silu1);
    // OTA=8, IR=16 -> grid (256/8=32, 512/16=32) = 1024 blocks
    xout3_kernel<512, 256, 8, 16><<<dim3(32, 32), 256, 0, stream>>>(
        (const float4*)basA1, siluT1, wcS, partS);
    xout_fin<256, 32><<<(256 * 256) / 256, 256, 0, stream>>>(partS, bias1, x2);
    stats_kernel<512, 256, 4, 4><<<dim3(256 / 4, 4), 256, 0, stream>>>(
        basB1, silu1, coef1, sb1, ssp1, partS);
    stats_fin<<<(256 * 512) / 256, 256, 0, stream>>>(
        partS, grid1, sc1, st1, 256 * 512, 4);
}

// Round 3
// 104.777 us; speedup vs baseline: 2.8395x; 1.3972x over previous
//
#include <hip/hip_runtime.h>
#include <math.h>

constexpr int BATCH = 256;

// ---------------------------------------------------------------------------
// Device bodies
// ---------------------------------------------------------------------------
__device__ __forceinline__ void merge_body(
    const float* __restrict__ coef, const float* __restrict__ ssp,
    const float* __restrict__ sb, float* __restrict__ wc, int s)
{
    float sspv = ssp[s], sbv = sb[s];
    const float4* c = (const float4*)(coef + (size_t)s * 8);
    float4 c0 = c[0], c1 = c[1];
    float4* w = (float4*)(wc + (size_t)s * 12);
    w[0] = make_float4(sspv * c0.x, sspv * c0.y, sspv * c0.z, sspv * c0.w);
    w[1] = make_float4(sspv * c1.x, sspv * c1.y, sspv * c1.z, sspv * c1.w);
    w[2] = make_float4(sbv, 0.f, 0.f, 0.f);
}

template <int I>
__device__ __forceinline__ void basis_body(
    const float* __restrict__ X, const float* __restrict__ grid,
    float4* __restrict__ basA4, float* __restrict__ siluT,
    float* __restrict__ basisB, float* __restrict__ siluN, int n)
{
    int b  = n / I;
    int ii = n % I;
    float x = X[n];

    float g[6];
#pragma unroll
    for (int k = 0; k < 6; ++k) g[k] = grid[(size_t)ii * 6 + k];
    float h = (g[5] - g[0]) * 0.2f;

    float t[12];
    t[0] = g[0] - 3.f * h; t[1] = g[0] - 2.f * h; t[2] = g[0] - h;
#pragma unroll
    for (int k = 0; k < 6; ++k) t[3 + k] = g[k];
    t[9] = g[5] + h; t[10] = g[5] + 2.f * h; t[11] = g[5] + 3.f * h;

    float Bv[11];
#pragma unroll
    for (int j = 0; j < 11; ++j)
        Bv[j] = (x >= t[j] && x < t[j + 1]) ? 1.0f : 0.0f;

#pragma unroll
    for (int d = 1; d <= 3; ++d) {
#pragma unroll
        for (int j = 0; j + d < 11; ++j) {
            float left  = (x - t[j]) / (t[j + d] - t[j]);
            float right = (t[j + d + 1] - x) / (t[j + d + 1] - t[j + 1]);
            Bv[j] = left * Bv[j] + right * Bv[j + 1];
        }
    }

    float sv = x / (1.0f + expf(-x));

    float4 v0 = make_float4(Bv[0], Bv[1], Bv[2], Bv[3]);
    float4 v1 = make_float4(Bv[4], Bv[5], Bv[6], Bv[7]);

    basA4[(size_t)(ii * 2 + 0) * BATCH + b] = v0;
    basA4[(size_t)(ii * 2 + 1) * BATCH + b] = v1;
    siluT[(size_t)ii * BATCH + b] = sv;

    float4* pB = (float4*)(basisB + (size_t)n * 8);
    pB[0] = v0; pB[1] = v1;
    siluN[n] = sv;
}

// xout sweep: block covers OTA outputs x IR inputs; threads = b, 4 b's/thread.
// xpart layout: [NSPLIT][O][BATCH], NSPLIT = I/IR.
template <int I, int O, int OTA, int IR>
__device__ __forceinline__ void xout_body(
    const float4* __restrict__ basA4, const float* __restrict__ siluT,
    const float* __restrict__ wc, float* __restrict__ xpart, int og, int sp)
{
    constexpr int OW  = OTA / 4;
    constexpr int NF4 = OTA * IR * 3;
    __shared__ float4 wcs[NF4];

    int t = threadIdx.x, lane = t & 63, w = t >> 6;
    int ii0 = sp * IR;

    for (int f = t; f < NF4; f += 256) {
        int o_r = f / (IR * 3), c = f % (IR * 3);
        wcs[f] = ((const float4*)(wc + ((size_t)(og * OTA + o_r) * I + ii0) * 12))[c];
    }
    __syncthreads();

    float acc[4][OW];
#pragma unroll
    for (int j = 0; j < 4; ++j)
#pragma unroll
        for (int q = 0; q < OW; ++q) acc[j][q] = 0.f;

    for (int i = 0; i < IR; ++i) {
        int ii = ii0 + i;
        float4 a0[4], a1[4]; float sv[4];
#pragma unroll
        for (int j = 0; j < 4; ++j) {
            int b = lane + 64 * j;
            a0[j] = basA4[(size_t)(ii * 2 + 0) * BATCH + b];
            a1[j] = basA4[(size_t)(ii * 2 + 1) * BATCH + b];
            sv[j] = siluT[(size_t)ii * BATCH + b];
        }
#pragma unroll
        for (int q = 0; q < OW; ++q) {
            const float* wr = (const float*)&wcs[((w * OW + q) * IR + i) * 3];
            float4 c0 = ((const float4*)wr)[0];
            float4 c1 = ((const float4*)wr)[1];
            float c8 = wr[8];
#pragma unroll
            for (int j = 0; j < 4; ++j) {
                acc[j][q] += a0[j].x * c0.x + a0[j].y * c0.y + a0[j].z * c0.z + a0[j].w * c0.w
                           + a1[j].x * c1.x + a1[j].y * c1.y + a1[j].z * c1.z + a1[j].w * c1.w
                           + sv[j] * c8;
            }
        }
    }

#pragma unroll
    for (int q = 0; q < OW; ++q) {
        int oo = og * OTA + w * OW + q;
#pragma unroll
        for (int j = 0; j < 4; ++j)
            xpart[((size_t)sp * O + oo) * BATCH + lane + 64 * j] = acc[j][q];
    }
}

template <int O, int NSPLIT>
__device__ __forceinline__ void xoutfin_body(
    const float* __restrict__ xpart, const float* __restrict__ bias,
    float* __restrict__ dst, int idx)
{
    int oo = idx / BATCH, b = idx % BATCH;
    float v = bias[oo];
#pragma unroll
    for (int k = 0; k < NSPLIT; ++k)
        v += xpart[((size_t)k * O + oo) * BATCH + b];
    dst[(size_t)b * O + oo] = v;
}

// stats sweep: threads = ii, register accum of sum|y|, sum y, sum y^2 over a
// b-chunk of BATCH/NCHUNK. spart layout: [NCHUNK][3][O*I]
template <int I, int O, int OTB, int NCHUNK>
__device__ __forceinline__ void stats_body(
    const float* __restrict__ basisB, const float* __restrict__ siluN,
    const float* __restrict__ coef, const float* __restrict__ sb,
    const float* __restrict__ ssp, float* __restrict__ spart, int og, int ch)
{
    constexpr int IC  = I / 256;
    constexpr int BCH = BATCH / NCHUNK;
    int t = threadIdx.x;

    float cf[OTB][IC][8];
    float sbr[OTB][IC], sspr[OTB][IC];
#pragma unroll
    for (int o = 0; o < OTB; ++o)
#pragma unroll
        for (int c = 0; c < IC; ++c) {
            int s = (og * OTB + o) * I + t + c * 256;
            const float4* p = (const float4*)(coef + (size_t)s * 8);
            float4 c0 = p[0], c1 = p[1];
            cf[o][c][0] = c0.x; cf[o][c][1] = c0.y; cf[o][c][2] = c0.z; cf[o][c][3] = c0.w;
            cf[o][c][4] = c1.x; cf[o][c][5] = c1.y; cf[o][c][6] = c1.z; cf[o][c][7] = c1.w;
            sbr[o][c] = sb[s]; sspr[o][c] = ssp[s];
        }

    float aab[OTB][IC], asum[OTB][IC], asq[OTB][IC];
#pragma unroll
    for (int o = 0; o < OTB; ++o)
#pragma unroll
        for (int c = 0; c < IC; ++c) { aab[o][c] = 0.f; asum[o][c] = 0.f; asq[o][c] = 0.f; }

    for (int bl = 0; bl < BCH; ++bl) {
        int b = ch * BCH + bl;
        float4 a0[IC], a1[IC]; float sv[IC];
#pragma unroll
        for (int c = 0; c < IC; ++c) {
            const float4* ba = (const float4*)(basisB + ((size_t)b * I + t + c * 256) * 8);
            a0[c] = ba[0]; a1[c] = ba[1];
            sv[c] = siluN[(size_t)b * I + t + c * 256];
        }
#pragma unroll
        for (int o = 0; o < OTB; ++o)
#pragma unroll
            for (int c = 0; c < IC; ++c) {
                float spl = a0[c].x * cf[o][c][0] + a0[c].y * cf[o][c][1]
                          + a0[c].z * cf[o][c][2] + a0[c].w * cf[o][c][3]
                          + a1[c].x * cf[o][c][4] + a1[c].y * cf[o][c][5]
                          + a1[c].z * cf[o][c][6] + a1[c].w * cf[o][c][7];
                float y = sbr[o][c] * sv[c] + sspr[o][c] * spl;
                aab[o][c] += fabsf(y);
                asum[o][c] += y;
                asq[o][c] = fmaf(y, y, asq[o][c]);
            }
    }

#pragma unroll
    for (int o = 0; o < OTB; ++o)
#pragma unroll
        for (int c = 0; c < IC; ++c) {
            int s = (og * OTB + o) * I + t + c * 256;
            size_t base = (size_t)ch * 3 * (size_t)O * I;
            spart[base + 0 * (size_t)O * I + s] = aab[o][c];
            spart[base + 1 * (size_t)O * I + s] = asum[o][c];
            spart[base + 2 * (size_t)O * I + s] = asq[o][c];
        }
}

__device__ __forceinline__ void statsfin_body(
    const float* __restrict__ spart, const float* __restrict__ grid,
    float* __restrict__ sc, float* __restrict__ st, int size, int nchunk, int s)
{
    float ab = 0.f, sm = 0.f, sq = 0.f;
    for (int k = 0; k < nchunk; ++k) {
        size_t base = (size_t)k * 3 * (size_t)size;
        ab += spart[base + s];
        sm += spart[base + (size_t)size + s];
        sq += spart[base + 2 * (size_t)size + s];
    }
    float range = grid[(size_t)s * 6 + 5] - grid[(size_t)s * 6 + 0] + 1e-4f;
    sc[s] = (ab * (1.0f / BATCH)) / range;
    float var = (sq - sm * sm * (1.0f / BATCH)) * (1.0f / (BATCH - 1));
    st[s] = sqrtf(fmaxf(var, 0.0f));
}

// ---------------------------------------------------------------------------
// 6 consolidated kernels
// ---------------------------------------------------------------------------
// K1: merge0 (512 blk) | merge1 (512 blk) | basis0 (256 blk)   -> 1280 blocks
__global__ __launch_bounds__(256) void k1_prep(
    const float* coef0, const float* ssp0, const float* sb0, float* wc0,
    const float* coef1, const float* ssp1, const float* sb1, float* wc1,
    const float* x, const float* grid0,
    float4* basA0, float* siluT0, float* basB0, float* silu0)
{
    int bid = blockIdx.x, t = threadIdx.x;
    if (bid < 512)       merge_body(coef0, ssp0, sb0, wc0, bid * 256 + t);
    else if (bid < 1024) merge_body(coef1, ssp1, sb1, wc1, (bid - 512) * 256 + t);
    else basis_body<256>(x, grid0, basA0, siluT0, basB0, silu0, (bid - 1024) * 256 + t);
}

// K2: xout0 (1024 blk) | stats0 (512 blk)                      -> 1536 blocks
__global__ __launch_bounds__(256) void k2_sweep0(
    const float4* basA0, const float* siluT0, const float* wc0, float* xpart0,
    const float* basB0, const float* silu0, const float* coef0,
    const float* sb0, const float* ssp0, float* spart0)
{
    int bid = blockIdx.x;
    if (bid < 1024) {
        xout_body<256, 512, 8, 16>(basA0, siluT0, wc0, xpart0, bid / 16, bid % 16);
    } else {
        int r = bid - 1024;  // 512 blocks: og in [0,64), ch in [0,8)
        stats_body<256, 512, 8, 8>(basB0, silu0, coef0, sb0, ssp0, spart0, r / 8, r % 8);
    }
}

// K3: xout_fin0 (512 blocks) -> xmid
__global__ __launch_bounds__(256) void k3_fin0(
    const float* xpart0, const float* bias0, float* xmid)
{
    xoutfin_body<512, 16>(xpart0, bias0, xmid, blockIdx.x * 256 + threadIdx.x);
}

// K4: basis1 (512 blocks)
__global__ __launch_bounds__(256) void k4_basis1(
    const float* xmid, const float* grid1,
    float4* basA1, float* siluT1, float* basB1, float* silu1)
{
    basis_body<512>(xmid, grid1, basA1, siluT1, basB1, silu1,
                    blockIdx.x * 256 + threadIdx.x);
}

// K5: xout1 (1024 blk) | stats1 (512 blk) | stats_fin0 (512 blk) -> 2048 blocks
__global__ __launch_bounds__(256) void k5_sweep1(
    const float4* basA1, const float* siluT1, const float* wc1, float* xpart1,
    const float* basB1, const float* silu1, const float* coef1,
    const float* sb1, const float* ssp1, float* spart1,
    const float* spart0, const float* grid0, float* sc0, float* st0)
{
    int bid = blockIdx.x;
    if (bid < 1024) {
        // og in [0,32), sp in [0,32)
        xout_body<512, 256, 8, 16>(basA1, siluT1, wc1, xpart1, bid / 32, bid % 32);
    } else if (bid < 1536) {
        int r = bid - 1024;  // og in [0,64), ch in [0,8)
        stats_body<512, 256, 4, 8>(basB1, silu1, coef1, sb1, ssp1, spart1, r / 8, r % 8);
    } else {
        statsfin_body(spart0, grid0, sc0, st0, 512 * 256, 8,
                      (bid - 1536) * 256 + threadIdx.x);
    }
}

// K6: xout_fin1 (256 blk) | stats_fin1 (512 blk)               -> 768 blocks
__global__ __launch_bounds__(256) void k6_fin1(
    const float* xpart1, const float* bias1, float* x2,
    const float* spart1, const float* grid1, float* sc1, float* st1)
{
    int bid = blockIdx.x;
    if (bid < 256) {
        xoutfin_body<256, 32>(xpart1, bias1, x2, bid * 256 + threadIdx.x);
    } else {
        statsfin_body(spart1, grid1, sc1, st1, 256 * 512, 8,
                      (bid - 256) * 256 + threadIdx.x);
    }
}

// ---------------------------------------------------------------------------
extern "C" void kernel_launch(void* const* d_in, const int* in_sizes, int n_in,
                              void* d_out, int out_size, void* d_ws, size_t ws_size,
                              hipStream_t stream)
{
    const float* x     = (const float*)d_in[0];
    const float* grid0 = (const float*)d_in[1];
    const float* coef0 = (const float*)d_in[2];
    const float* sb0   = (const float*)d_in[3];
    const float* ssp0  = (const float*)d_in[4];
    const float* bias0 = (const float*)d_in[5];
    const float* grid1 = (const float*)d_in[6];
    const float* coef1 = (const float*)d_in[7];
    const float* sb1   = (const float*)d_in[8];
    const float* ssp1  = (const float*)d_in[9];
    const float* bias1 = (const float*)d_in[10];

    float* out = (float*)d_out;
    float* x2  = out;                 // (256,256)
    float* sc0 = out + 65536;         // (512,256)
    float* st0 = out + 196608;        // (512,256)
    float* sc1 = out + 327680;        // (256,512)
    float* st1 = out + 458752;        // (256,512)

    // Workspace (all regions disjoint; ~71 MB of ws):
    float* w = (float*)d_ws;
    float* basA0  = w; w += 256 * 256 * 8;      // 2 float4 per (ii,b)
    float* siluT0 = w; w += 256 * 256;
    float* basB0  = w; w += 256 * 256 * 8;
    float* silu0  = w; w += 256 * 256;
    float* basA1  = w; w += 512 * 256 * 8;
    float* siluT1 = w; w += 512 * 256;
    float* basB1  = w; w += 512 * 256 * 8;
    float* silu1  = w; w += 512 * 256;
    float* wc0    = w; w += 512 * 256 * 12;
    float* wc1    = w; w += 512 * 256 * 12;
    float* xmid   = w; w += 256 * 512;
    float* xpart0 = w; w += 16 * 512 * 256;     // [16][512][256]
    float* xpart1 = w; w += 32 * 256 * 256;     // [32][256][256]
    float* spart0 = w; w += 8 * 3 * 512 * 256;  // [8][3][131072]
    float* spart1 = w; w += 8 * 3 * 256 * 512;  // [8][3][131072]

    k1_prep<<<1280, 256, 0, stream>>>(
        coef0, ssp0, sb0, wc0, coef1, ssp1, sb1, wc1,
        x, grid0, (float4*)basA0, siluT0, basB0, silu0);

    k2_sweep0<<<1536, 256, 0, stream>>>(
        (const float4*)basA0, siluT0, wc0, xpart0,
        basB0, silu0, coef0, sb0, ssp0, spart0);

    k3_fin0<<<512, 256, 0, stream>>>(xpart0, bias0, xmid);

    k4_basis1<<<512, 256, 0, stream>>>(
        xmid, grid1, (float4*)basA1, siluT1, basB1, silu1);

    k5_sweep1<<<2048, 256, 0, stream>>>(
        (const float4*)basA1, siluT1, wc1, xpart1,
        basB1, silu1, coef1, sb1, ssp1, spart1,
        spart0, grid0, sc0, st0);

    k6_fin1<<<768, 256, 0, stream>>>(
        xpart1, bias1, x2, spart1, grid1, sc1, st1);
}

// Round 4
// 90.763 us; speedup vs baseline: 3.2779x; 1.1544x over previous
//
#include <hip/hip_runtime.h>
#include <math.h>

constexpr int BATCH = 256;

// ---------------------------------------------------------------------------
// merge: wc[s*12+k] = ssp[s]*coef[s*8+k] (k<8), wc[s*12+8] = sb[s]
// ---------------------------------------------------------------------------
__device__ __forceinline__ void merge_body(
    const float* __restrict__ coef, const float* __restrict__ ssp,
    const float* __restrict__ sb, float* __restrict__ wc, int s)
{
    float sspv = ssp[s], sbv = sb[s];
    const float4* c = (const float4*)(coef + (size_t)s * 8);
    float4 c0 = c[0], c1 = c[1];
    float4* w = (float4*)(wc + (size_t)s * 12);
    w[0] = make_float4(sspv * c0.x, sspv * c0.y, sspv * c0.z, sspv * c0.w);
    w[1] = make_float4(sspv * c1.x, sspv * c1.y, sspv * c1.z, sspv * c1.w);
    w[2] = make_float4(sbv, 0.f, 0.f, 0.f);
}

// ---------------------------------------------------------------------------
// basis core: 8 cubic B-spline values + silu for one (b, ii).
//   basA4[(ii*2+h)*B + b], siluT[ii*B+b]   (xout layout, b-fastest)
//   basB[(b*I+ii)*8..], siluN[b*I+ii]      (stats layout, ii-fastest)
// ---------------------------------------------------------------------------
__device__ __forceinline__ void basis_core(
    float x, const float* __restrict__ grid, int ii, int b, int I,
    float4* __restrict__ basA4, float* __restrict__ siluT,
    float* __restrict__ basB, float* __restrict__ siluN)
{
    float g[6];
#pragma unroll
    for (int k = 0; k < 6; ++k) g[k] = grid[(size_t)ii * 6 + k];
    float h = (g[5] - g[0]) * 0.2f;

    float t[12];
    t[0] = g[0] - 3.f * h; t[1] = g[0] - 2.f * h; t[2] = g[0] - h;
#pragma unroll
    for (int k = 0; k < 6; ++k) t[3 + k] = g[k];
    t[9] = g[5] + h; t[10] = g[5] + 2.f * h; t[11] = g[5] + 3.f * h;

    float Bv[11];
#pragma unroll
    for (int j = 0; j < 11; ++j)
        Bv[j] = (x >= t[j] && x < t[j + 1]) ? 1.0f : 0.0f;

#pragma unroll
    for (int d = 1; d <= 3; ++d) {
#pragma unroll
        for (int j = 0; j + d < 11; ++j) {
            float left  = (x - t[j]) / (t[j + d] - t[j]);
            float right = (t[j + d + 1] - x) / (t[j + d + 1] - t[j + 1]);
            Bv[j] = left * Bv[j] + right * Bv[j + 1];
        }
    }

    float sv = x / (1.0f + expf(-x));

    float4 v0 = make_float4(Bv[0], Bv[1], Bv[2], Bv[3]);
    float4 v1 = make_float4(Bv[4], Bv[5], Bv[6], Bv[7]);

    basA4[(size_t)(ii * 2 + 0) * BATCH + b] = v0;
    basA4[(size_t)(ii * 2 + 1) * BATCH + b] = v1;
    siluT[(size_t)ii * BATCH + b] = sv;
    float4* pB = (float4*)(basB + ((size_t)b * I + ii) * 8);
    pB[0] = v0; pB[1] = v1;
    siluN[(size_t)b * I + ii] = sv;
}

// ---------------------------------------------------------------------------
// xout sweep: OTA=16 outputs x IR=16 inputs per block; threads = b (4/thread).
// wc tile staged in LDS (broadcast reads). xpart: [I/IR][O][BATCH]
// ---------------------------------------------------------------------------
template <int I, int O>
__device__ __forceinline__ void xout_body(
    const float4* __restrict__ basA4, const float* __restrict__ siluT,
    const float* __restrict__ wc, float* __restrict__ xpart, int og, int sp)
{
    constexpr int OTA = 16, IR = 16;
    constexpr int NF4 = OTA * IR * 3;   // 768 float4 = 12 KB
    __shared__ float4 wcs[NF4];

    int t = threadIdx.x, lane = t & 63, w = t >> 6;
    int ii0 = sp * IR;

#pragma unroll
    for (int u = 0; u < 3; ++u) {
        int f = t + u * 256;
        int o_r = f / (IR * 3), c = f % (IR * 3);
        wcs[f] = ((const float4*)(wc + ((size_t)(og * OTA + o_r) * I + ii0) * 12))[c];
    }
    __syncthreads();

    float acc[4][4];
#pragma unroll
    for (int j = 0; j < 4; ++j)
#pragma unroll
        for (int q = 0; q < 4; ++q) acc[j][q] = 0.f;

    for (int i = 0; i < IR; ++i) {
        int ii = ii0 + i;
        float4 a0[4], a1[4]; float sv[4];
#pragma unroll
        for (int j = 0; j < 4; ++j) {
            int b = lane + 64 * j;
            a0[j] = basA4[(size_t)(ii * 2 + 0) * BATCH + b];
            a1[j] = basA4[(size_t)(ii * 2 + 1) * BATCH + b];
            sv[j] = siluT[(size_t)ii * BATCH + b];
        }
#pragma unroll
        for (int q = 0; q < 4; ++q) {
            const float* wr = (const float*)&wcs[((w * 4 + q) * IR + i) * 3];
            float4 c0 = ((const float4*)wr)[0];
            float4 c1 = ((const float4*)wr)[1];
            float c8 = wr[8];
#pragma unroll
            for (int j = 0; j < 4; ++j) {
                acc[j][q] += a0[j].x * c0.x + a0[j].y * c0.y + a0[j].z * c0.z + a0[j].w * c0.w
                           + a1[j].x * c1.x + a1[j].y * c1.y + a1[j].z * c1.z + a1[j].w * c1.w
                           + sv[j] * c8;
            }
        }
    }

#pragma unroll
    for (int q = 0; q < 4; ++q) {
        int oo = og * OTA + w * 4 + q;
#pragma unroll
        for (int j = 0; j < 4; ++j)
            xpart[((size_t)sp * O + oo) * BATCH + lane + 64 * j] = acc[j][q];
    }
}

// ---------------------------------------------------------------------------
// stats sweep: threads = ii (one ii each, ii = isp*256+t), OTB o's in regs,
// accumulate over b-chunk of BCH. Uses merged wc (9 FMA per y).
// spart: [NCHUNK][3][O*I]
// ---------------------------------------------------------------------------
template <int I, int O, int OTB, int BCH>
__device__ __forceinline__ void stats_body(
    const float* __restrict__ basB, const float* __restrict__ siluN,
    const float* __restrict__ wc, float* __restrict__ spart,
    int og, int ch, int isp)
{
    int t = threadIdx.x;
    int ii = isp * 256 + t;

    float wcr[OTB][9];
#pragma unroll
    for (int o = 0; o < OTB; ++o) {
        int s = (og * OTB + o) * I + ii;
        const float4* p = (const float4*)(wc + (size_t)s * 12);
        float4 c0 = p[0], c1 = p[1];
        wcr[o][0] = c0.x; wcr[o][1] = c0.y; wcr[o][2] = c0.z; wcr[o][3] = c0.w;
        wcr[o][4] = c1.x; wcr[o][5] = c1.y; wcr[o][6] = c1.z; wcr[o][7] = c1.w;
        wcr[o][8] = wc[(size_t)s * 12 + 8];
    }

    float aab[OTB], asum[OTB], asq[OTB];
#pragma unroll
    for (int o = 0; o < OTB; ++o) { aab[o] = 0.f; asum[o] = 0.f; asq[o] = 0.f; }

    for (int bl = 0; bl < BCH; ++bl) {
        int b = ch * BCH + bl;
        const float4* ba = (const float4*)(basB + ((size_t)b * I + ii) * 8);
        float4 a0 = ba[0], a1 = ba[1];
        float sv = siluN[(size_t)b * I + ii];
#pragma unroll
        for (int o = 0; o < OTB; ++o) {
            float y = wcr[o][8] * sv;
            y = fmaf(a0.x, wcr[o][0], y); y = fmaf(a0.y, wcr[o][1], y);
            y = fmaf(a0.z, wcr[o][2], y); y = fmaf(a0.w, wcr[o][3], y);
            y = fmaf(a1.x, wcr[o][4], y); y = fmaf(a1.y, wcr[o][5], y);
            y = fmaf(a1.z, wcr[o][6], y); y = fmaf(a1.w, wcr[o][7], y);
            aab[o] += fabsf(y);
            asum[o] += y;
            asq[o] = fmaf(y, y, asq[o]);
        }
    }

    size_t OI = (size_t)O * I;
    size_t base = (size_t)ch * 3 * OI;
#pragma unroll
    for (int o = 0; o < OTB; ++o) {
        int s = (og * OTB + o) * I + ii;
        spart[base + s]          = aab[o];
        spart[base + OI + s]     = asum[o];
        spart[base + 2 * OI + s] = asq[o];
    }
}

__device__ __forceinline__ void statsfin_body(
    const float* __restrict__ spart, const float* __restrict__ grid,
    float* __restrict__ sc, float* __restrict__ st, int size, int nchunk, int s)
{
    float ab = 0.f, sm = 0.f, sq = 0.f;
    for (int k = 0; k < nchunk; ++k) {
        size_t base = (size_t)k * 3 * (size_t)size;
        ab += spart[base + s];
        sm += spart[base + (size_t)size + s];
        sq += spart[base + 2 * (size_t)size + s];
    }
    float range = grid[(size_t)s * 6 + 5] - grid[(size_t)s * 6 + 0] + 1e-4f;
    sc[s] = (ab * (1.0f / BATCH)) / range;
    float var = (sq - sm * sm * (1.0f / BATCH)) * (1.0f / (BATCH - 1));
    st[s] = sqrtf(fmaxf(var, 0.0f));
}

// ---------------------------------------------------------------------------
// K1: merge0 (512) | merge1 (512) | basis0 tiled 16x16 (256)  -> 1280 blocks
// ---------------------------------------------------------------------------
__global__ __launch_bounds__(256) void k1_prep(
    const float* __restrict__ coef0, const float* __restrict__ ssp0,
    const float* __restrict__ sb0, float* __restrict__ wc0,
    const float* __restrict__ coef1, const float* __restrict__ ssp1,
    const float* __restrict__ sb1, float* __restrict__ wc1,
    const float* __restrict__ x, const float* __restrict__ grid0,
    float4* __restrict__ basA0, float* __restrict__ siluT0,
    float* __restrict__ basB0, float* __restrict__ silu0)
{
    int bid = blockIdx.x, t = threadIdx.x;
    if (bid < 512)       { merge_body(coef0, ssp0, sb0, wc0, bid * 256 + t); return; }
    if (bid < 1024)      { merge_body(coef1, ssp1, sb1, wc1, (bid - 512) * 256 + t); return; }
    int tile = bid - 1024;                  // 256 tiles over (B/16) x (I/16)
    int ii = (tile % 16) * 16 + (t >> 4);   // I = 256
    int b  = (tile / 16) * 16 + (t & 15);
    float xv = x[(size_t)b * 256 + ii];
    basis_core(xv, grid0, ii, b, 256, basA0, siluT0, basB0, silu0);
}

// ---------------------------------------------------------------------------
// K2: xout0 (512: og32 x sp16) | stats0 (1024: og64 x ch16)   -> 1536 blocks
// ---------------------------------------------------------------------------
__global__ __launch_bounds__(256) void k2_sweep0(
    const float4* __restrict__ basA0, const float* __restrict__ siluT0,
    const float* __restrict__ wc0, float* __restrict__ xpart0,
    const float* __restrict__ basB0, const float* __restrict__ silu0,
    float* __restrict__ spart0)
{
    int bid = blockIdx.x;
    if (bid < 512) {
        xout_body<256, 512>(basA0, siluT0, wc0, xpart0, bid / 16, bid % 16);
    } else {
        int r = bid - 512;
        stats_body<256, 512, 8, 16>(basB0, silu0, wc0, spart0, r / 16, r % 16, 0);
    }
}

// ---------------------------------------------------------------------------
// K3: basis1 tiled (512 tiles) with fused xmid = sum(xpart0) + bias0
// ---------------------------------------------------------------------------
__global__ __launch_bounds__(256) void k3_basis1(
    const float* __restrict__ xpart0, const float* __restrict__ bias0,
    const float* __restrict__ grid1,
    float4* __restrict__ basA1, float* __restrict__ siluT1,
    float* __restrict__ basB1, float* __restrict__ silu1)
{
    int tile = blockIdx.x, t = threadIdx.x;
    int ii = (tile % 32) * 16 + (t >> 4);   // I = 512 (= O of layer 0)
    int b  = (tile / 32) * 16 + (t & 15);
    float xv = bias0[ii];
#pragma unroll
    for (int k = 0; k < 16; ++k)
        xv += xpart0[(size_t)k * 512 * 256 + (size_t)ii * 256 + b];
    basis_core(xv, grid1, ii, b, 512, basA1, siluT1, basB1, silu1);
}

// ---------------------------------------------------------------------------
// K4: xout1 (512: og16 x sp32) | stats1 (1024: og32 x ch16 x isp2)
//     | statsfin0 (512)                                      -> 2048 blocks
// ---------------------------------------------------------------------------
__global__ __launch_bounds__(256) void k4_sweep1(
    const float4* __restrict__ basA1, const float* __restrict__ siluT1,
    const float* __restrict__ wc1, float* __restrict__ xpart1,
    const float* __restrict__ basB1, const float* __restrict__ silu1,
    float* __restrict__ spart1,
    const float* __restrict__ spart0, const float* __restrict__ grid0,
    float* __restrict__ sc0, float* __restrict__ st0)
{
    int bid = blockIdx.x;
    if (bid < 512) {
        xout_body<512, 256>(basA1, siluT1, wc1, xpart1, bid / 32, bid % 32);
    } else if (bid < 1536) {
        int r = bid - 512;
        int og = r / 32, rem = r % 32;
        stats_body<512, 256, 8, 16>(basB1, silu1, wc1, spart1, og, rem % 16, rem / 16);
    } else {
        statsfin_body(spart0, grid0, sc0, st0, 512 * 256, 16,
                      (bid - 1536) * 256 + threadIdx.x);
    }
}

// ---------------------------------------------------------------------------
// K5: xout_fin1 (256) | statsfin1 (512)                      -> 768 blocks
// ---------------------------------------------------------------------------
__global__ __launch_bounds__(256) void k5_fin(
    const float* __restrict__ xpart1, const float* __restrict__ bias1,
    float* __restrict__ x2,
    const float* __restrict__ spart1, const float* __restrict__ grid1,
    float* __restrict__ sc1, float* __restrict__ st1)
{
    int bid = blockIdx.x, t = threadIdx.x;
    if (bid < 256) {
        int oo = bid, b = t;
        float v = bias1[oo];
#pragma unroll
        for (int k = 0; k < 32; ++k)
            v += xpart1[(size_t)k * 256 * 256 + (size_t)oo * 256 + b];
        x2[(size_t)b * 256 + oo] = v;
    } else {
        statsfin_body(spart1, grid1, sc1, st1, 256 * 512, 16,
                      (bid - 256) * 256 + t);
    }
}

// ---------------------------------------------------------------------------
extern "C" void kernel_launch(void* const* d_in, const int* in_sizes, int n_in,
                              void* d_out, int out_size, void* d_ws, size_t ws_size,
                              hipStream_t stream)
{
    const float* x     = (const float*)d_in[0];
    const float* grid0 = (const float*)d_in[1];
    const float* coef0 = (const float*)d_in[2];
    const float* sb0   = (const float*)d_in[3];
    const float* ssp0  = (const float*)d_in[4];
    const float* bias0 = (const float*)d_in[5];
    const float* grid1 = (const float*)d_in[6];
    const float* coef1 = (const float*)d_in[7];
    const float* sb1   = (const float*)d_in[8];
    const float* ssp1  = (const float*)d_in[9];
    const float* bias1 = (const float*)d_in[10];

    float* out = (float*)d_out;
    float* x2  = out;                 // (256,256)
    float* sc0 = out + 65536;         // (512,256)
    float* st0 = out + 196608;        // (512,256)
    float* sc1 = out + 327680;        // (256,512)
    float* st1 = out + 458752;        // (256,512)

    // Workspace (~94 MB, all disjoint):
    float* w = (float*)d_ws;
    float* basA0  = w; w += 256 * 256 * 8;
    float* siluT0 = w; w += 256 * 256;
    float* basB0  = w; w += 256 * 256 * 8;
    float* silu0  = w; w += 256 * 256;
    float* basA1  = w; w += 512 * 256 * 8;
    float* siluT1 = w; w += 512 * 256;
    float* basB1  = w; w += 512 * 256 * 8;
    float* silu1  = w; w += 512 * 256;
    float* wc0    = w; w += 512 * 256 * 12;
    float* wc1    = w; w += 512 * 256 * 12;
    float* xpart0 = w; w += 16 * 512 * 256;      // [16][512][256]
    float* xpart1 = w; w += 32 * 256 * 256;      // [32][256][256]
    float* spart0 = w; w += 16 * 3 * 512 * 256;  // [16][3][131072]
    float* spart1 = w; w += 16 * 3 * 256 * 512;  // [16][3][131072]

    k1_prep<<<1280, 256, 0, stream>>>(
        coef0, ssp0, sb0, wc0, coef1, ssp1, sb1, wc1,
        x, grid0, (float4*)basA0, siluT0, basB0, silu0);

    k2_sweep0<<<1536, 256, 0, stream>>>(
        (const float4*)basA0, siluT0, wc0, xpart0, basB0, silu0, spart0);

    k3_basis1<<<512, 256, 0, stream>>>(
        xpart0, bias0, grid1, (float4*)basA1, siluT1, basB1, silu1);

    k4_sweep1<<<2048, 256, 0, stream>>>(
        (const float4*)basA1, siluT1, wc1, xpart1, basB1, silu1, spart1,
        spart0, grid0, sc0, st0);

    k5_fin<<<768, 256, 0, stream>>>(
        xpart1, bias1, x2, spart1, grid1, sc1, st1);
}